// Round 1
// baseline (20069.003 us; speedup 1.0000x reference)
//
#include <hip/hip_runtime.h>
#include <hip/hip_bf16.h>

typedef _Float16 half8 __attribute__((ext_vector_type(8)));
typedef _Float16 half4v __attribute__((ext_vector_type(4)));
typedef float f32x4 __attribute__((ext_vector_type(4)));

#define BB 64
#define SS 512
#define HH 1024
#define G4 4096

__device__ __forceinline__ float sigmf(float x) { return 1.0f / (1.0f + __expf(-x)); }
__device__ __forceinline__ float tanhfast(float x) { return 2.0f / (1.0f + __expf(-2.0f * x)) - 1.0f; }

// inputs[b][s][h] (f32) -> x16[s][b][h] (fp16), time-major
__global__ __launch_bounds__(256) void convert_x_kernel(const float* __restrict__ in,
                                                        _Float16* __restrict__ x16) {
  size_t idx = (size_t)blockIdx.x * 256 + threadIdx.x;  // 8,388,608 float4s
  int h4 = (int)(idx & 255);
  int s  = (int)((idx >> 8) & 511);
  int b  = (int)(idx >> 17);
  const float4* src = (const float4*)in;
  float4 v = src[((size_t)b * SS + s) * 256 + h4];
  half4v hv = { (_Float16)v.x, (_Float16)v.y, (_Float16)v.z, (_Float16)v.w };
  *(half4v*)(x16 + ((size_t)s * BB + b) * HH + (size_t)h4 * 4) = hv;
}

// W[l][k][n] (f32) -> wT[m][n][k] (fp16); m: 0=Wx l0, 1=Wx l1, 2=Wh l0, 3=Wh l1
__global__ __launch_bounds__(256) void convert_w_kernel(const float* __restrict__ Wx,
                                                        const float* __restrict__ Wh,
                                                        _Float16* __restrict__ wT) {
  __shared__ float tile[32][33];
  int m = blockIdx.x >> 12;        // 4096 tiles per matrix
  int t = blockIdx.x & 4095;
  int tn = t & 127, tk = t >> 7;   // 128 n-tiles, 32 k-tiles
  int l = m & 1, which = m >> 1;
  const float* src = (which ? Wh : Wx) + (size_t)l * HH * G4;
  int tx = threadIdx.x & 31, ty = threadIdx.x >> 5;  // ty 0..7
#pragma unroll
  for (int p = 0; p < 4; ++p) {
    int k = tk * 32 + ty + 8 * p, n = tn * 32 + tx;
    tile[ty + 8 * p][tx] = src[(size_t)k * G4 + n];
  }
  __syncthreads();
  _Float16* dst = wT + (size_t)m * G4 * HH;
#pragma unroll
  for (int p = 0; p < 4; ++p) {
    int n = tn * 32 + ty + 8 * p, k = tk * 32 + tx;
    dst[(size_t)n * HH + k] = (_Float16)tile[tx][ty + 8 * p];
  }
}

// One combined pipelined step: blocks 0..63 = layer1 step t, blocks 64..127 = layer2 step t-1.
// Each block: 16 h-cols (64 feat cols = 4 gates x 16), all 64 batch rows.
// feat = A1 @ Wa + A2 @ Wb + bx + bh, via fp16 MFMA 16x16x32, fp32 accum.
__global__ __launch_bounds__(256) void lstm_step_kernel(
    const _Float16* __restrict__ x16, const _Float16* __restrict__ wT,
    const float* __restrict__ bx, const float* __restrict__ bh,
    _Float16* __restrict__ h1buf, _Float16* __restrict__ h2buf,
    float* __restrict__ c1, float* __restrict__ c2,
    float* __restrict__ hmax, int t) {
  int blk = blockIdx.x;
  int layer = blk >> 6;
  int j = blk & 63;
  int tp;
  const _Float16 *A1, *A2, *Bx, *Bh;
  float* cbuf;
  _Float16* hout;
  if (layer == 0) {
    if (t >= SS) return;
    tp = t;
    A1 = x16 + (size_t)tp * BB * HH;                  // x_t
    A2 = h1buf + (size_t)((tp + 1) & 1) * BB * HH;    // h1_{t-1}
    Bx = wT;                                          // Wx l0
    Bh = wT + (size_t)2 * G4 * HH;                    // Wh l0
    cbuf = c1;
    hout = h1buf + (size_t)(tp & 1) * BB * HH;
  } else {
    if (t < 1) return;
    tp = t - 1;
    A1 = h1buf + (size_t)(tp & 1) * BB * HH;          // h1_{tp} (written last launch)
    A2 = h2buf + (size_t)((tp + 1) & 1) * BB * HH;    // h2_{tp-1}
    Bx = wT + (size_t)1 * G4 * HH;                    // Wx l1
    Bh = wT + (size_t)3 * G4 * HH;                    // Wh l1
    cbuf = c2;
    hout = h2buf + (size_t)(tp & 1) * BB * HH;
  }
  const float* bxl = bx + (size_t)layer * G4;
  const float* bhl = bh + (size_t)layer * G4;

  int tid = threadIdx.x;
  int w = tid >> 6, l = tid & 63;
  int lane16 = l & 15, lgr = l >> 4;

  f32x4 acc0 = {0.f, 0.f, 0.f, 0.f};
  f32x4 acc1 = {0.f, 0.f, 0.f, 0.f};
  f32x4 acc2 = {0.f, 0.f, 0.f, 0.f};
  f32x4 acc3 = {0.f, 0.f, 0.f, 0.f};

  int colbase = j * 16 + lane16;
  const _Float16* a1p = A1 + (size_t)(16 * w + lane16) * HH + 8 * lgr;
  const _Float16* a2p = A2 + (size_t)(16 * w + lane16) * HH + 8 * lgr;
  const _Float16* bxp0 = Bx + (size_t)(0 * 1024 + colbase) * HH + 8 * lgr;
  const _Float16* bxp1 = Bx + (size_t)(1 * 1024 + colbase) * HH + 8 * lgr;
  const _Float16* bxp2 = Bx + (size_t)(2 * 1024 + colbase) * HH + 8 * lgr;
  const _Float16* bxp3 = Bx + (size_t)(3 * 1024 + colbase) * HH + 8 * lgr;
  const _Float16* bhp0 = Bh + (size_t)(0 * 1024 + colbase) * HH + 8 * lgr;
  const _Float16* bhp1 = Bh + (size_t)(1 * 1024 + colbase) * HH + 8 * lgr;
  const _Float16* bhp2 = Bh + (size_t)(2 * 1024 + colbase) * HH + 8 * lgr;
  const _Float16* bhp3 = Bh + (size_t)(3 * 1024 + colbase) * HH + 8 * lgr;

  for (int kk = 0; kk < HH; kk += 32) {
    half8 a = *(const half8*)(a1p + kk);
    acc0 = __builtin_amdgcn_mfma_f32_16x16x32_f16(a, *(const half8*)(bxp0 + kk), acc0, 0, 0, 0);
    acc1 = __builtin_amdgcn_mfma_f32_16x16x32_f16(a, *(const half8*)(bxp1 + kk), acc1, 0, 0, 0);
    acc2 = __builtin_amdgcn_mfma_f32_16x16x32_f16(a, *(const half8*)(bxp2 + kk), acc2, 0, 0, 0);
    acc3 = __builtin_amdgcn_mfma_f32_16x16x32_f16(a, *(const half8*)(bxp3 + kk), acc3, 0, 0, 0);
  }
  for (int kk = 0; kk < HH; kk += 32) {
    half8 a = *(const half8*)(a2p + kk);
    acc0 = __builtin_amdgcn_mfma_f32_16x16x32_f16(a, *(const half8*)(bhp0 + kk), acc0, 0, 0, 0);
    acc1 = __builtin_amdgcn_mfma_f32_16x16x32_f16(a, *(const half8*)(bhp1 + kk), acc1, 0, 0, 0);
    acc2 = __builtin_amdgcn_mfma_f32_16x16x32_f16(a, *(const half8*)(bhp2 + kk), acc2, 0, 0, 0);
    acc3 = __builtin_amdgcn_mfma_f32_16x16x32_f16(a, *(const half8*)(bhp3 + kk), acc3, 0, 0, 0);
  }

  // Epilogue: C/D frag mapping col=lane&15, row=4*(lane>>4)+reg.
  // Same (lane, reg) across the 4 gate accumulators = same (row, hcol): no cross-lane needed.
  int hcol = colbase;
  float bi = bxl[hcol] + bhl[hcol];
  float bf = bxl[1024 + hcol] + bhl[1024 + hcol];
  float bg = bxl[2048 + hcol] + bhl[2048 + hcol];
  float bo = bxl[3072 + hcol] + bhl[3072 + hcol];
#pragma unroll
  for (int r = 0; r < 4; ++r) {
    int row = 16 * w + 4 * lgr + r;
    float vi = acc0[r] + bi;
    float vf = acc1[r] + bf;
    float vg = acc2[r] + bg;
    float vo = acc3[r] + bo;
    float ig = sigmf(vi), fg = sigmf(vf), gg = tanhfast(vg), og = sigmf(vo);
    size_t ci = (size_t)row * HH + hcol;
    float cn = fg * cbuf[ci] + ig * gg;
    float hn = tanhfast(cn) * og;
    cbuf[ci] = cn;
    hout[ci] = (_Float16)hn;
    if (layer) {
      if (tp == 0) hmax[ci] = hn;
      else hmax[ci] = fmaxf(hmax[ci], hn);
    }
  }
}

__global__ __launch_bounds__(320) void classify_kernel(const float* __restrict__ hmax,
                                                       const float* __restrict__ Wp,
                                                       const float* __restrict__ bp,
                                                       float* __restrict__ out) {
  int tid = threadIdx.x;  // 320 = 64*5
  int b = tid / 5, jj = tid % 5;
  float s = bp[jj];
  const float* hp = hmax + (size_t)b * HH;
  for (int h = 0; h < HH; ++h) s = fmaf(hp[h], Wp[h * 5 + jj], s);
  out[tid] = s;
}

extern "C" void kernel_launch(void* const* d_in, const int* in_sizes, int n_in,
                              void* d_out, int out_size, void* d_ws, size_t ws_size,
                              hipStream_t stream) {
  const float* inputs = (const float*)d_in[0];
  const float* Wx = (const float*)d_in[1];
  const float* bx = (const float*)d_in[2];
  const float* Wh = (const float*)d_in[3];
  const float* bh = (const float*)d_in[4];
  const float* Wp = (const float*)d_in[5];
  const float* bp = (const float*)d_in[6];
  float* out = (float*)d_out;

  char* ws = (char*)d_ws;
  _Float16* x16   = (_Float16*)(ws + 0);           // 512*64*1024*2       = 67,108,864
  _Float16* wT    = (_Float16*)(ws + 67108864);    // 4*4096*1024*2       = 33,554,432
  _Float16* h1buf = (_Float16*)(ws + 100663296);   // 2*64*1024*2         = 262,144
  _Float16* h2buf = (_Float16*)(ws + 100925440);   // 262,144
  float*    c1    = (float*)(ws + 101187584);      // 64*1024*4           = 262,144
  float*    c2    = (float*)(ws + 101449728);      // 262,144
  float*    hmax  = (float*)(ws + 101711872);      // 262,144  (end ~97.2 MB)

  // zero initial h/c state (ws is poisoned; must be deterministic every call)
  hipMemsetAsync(h1buf, 0, 262144, stream);
  hipMemsetAsync(h2buf, 0, 262144, stream);
  hipMemsetAsync(c1, 0, 262144, stream);
  hipMemsetAsync(c2, 0, 262144, stream);

  convert_x_kernel<<<32768, 256, 0, stream>>>(inputs, x16);
  convert_w_kernel<<<16384, 256, 0, stream>>>(Wx, Wh, wT);

  // Pipelined: launch t does layer1 step t (blocks 0..63) and layer2 step t-1 (blocks 64..127)
  for (int t = 0; t <= SS; ++t) {
    lstm_step_kernel<<<128, 256, 0, stream>>>(x16, wT, bx, bh, h1buf, h2buf, c1, c2, hmax, t);
  }
  classify_kernel<<<1, 320, 0, stream>>>(hmax, Wp, bp, out);
}

// Round 2
// 6380.970 us; speedup vs baseline: 3.1451x; 3.1451x over previous
//
#include <hip/hip_runtime.h>
#include <hip/hip_bf16.h>

typedef _Float16 half8 __attribute__((ext_vector_type(8)));
typedef _Float16 half4v __attribute__((ext_vector_type(4)));
typedef float f32x4 __attribute__((ext_vector_type(4)));

#define BB 64
#define SS 512
#define HH 1024
#define G4 4096

__device__ __forceinline__ float sigmf(float x) { return 1.0f / (1.0f + __expf(-x)); }
__device__ __forceinline__ float tanhfast(float x) { return 2.0f / (1.0f + __expf(-2.0f * x)) - 1.0f; }

// inputs[b][s][h] (f32) -> x16[s][b][h] (fp16), time-major
__global__ __launch_bounds__(256) void convert_x_kernel(const float* __restrict__ in,
                                                        _Float16* __restrict__ x16) {
  size_t idx = (size_t)blockIdx.x * 256 + threadIdx.x;  // 8,388,608 float4s
  int h4 = (int)(idx & 255);
  int s  = (int)((idx >> 8) & 511);
  int b  = (int)(idx >> 17);
  const float4* src = (const float4*)in;
  float4 v = src[((size_t)b * SS + s) * 256 + h4];
  half4v hv = { (_Float16)v.x, (_Float16)v.y, (_Float16)v.z, (_Float16)v.w };
  *(half4v*)(x16 + ((size_t)s * BB + b) * HH + (size_t)h4 * 4) = hv;
}

// W[l][k][n] (f32) -> wT[m][n][k] (fp16); m: 0=Wx l0, 1=Wx l1, 2=Wh l0, 3=Wh l1
__global__ __launch_bounds__(256) void convert_w_kernel(const float* __restrict__ Wx,
                                                        const float* __restrict__ Wh,
                                                        _Float16* __restrict__ wT) {
  __shared__ float tile[32][33];
  int m = blockIdx.x >> 12;        // 4096 tiles per matrix
  int t = blockIdx.x & 4095;
  int tn = t & 127, tk = t >> 7;   // 128 n-tiles, 32 k-tiles
  int l = m & 1, which = m >> 1;
  const float* src = (which ? Wh : Wx) + (size_t)l * HH * G4;
  int tx = threadIdx.x & 31, ty = threadIdx.x >> 5;  // ty 0..7
#pragma unroll
  for (int p = 0; p < 4; ++p) {
    int k = tk * 32 + ty + 8 * p, n = tn * 32 + tx;
    tile[ty + 8 * p][tx] = src[(size_t)k * G4 + n];
  }
  __syncthreads();
  _Float16* dst = wT + (size_t)m * G4 * HH;
#pragma unroll
  for (int p = 0; p < 4; ++p) {
    int n = tn * 32 + ty + 8 * p, k = tk * 32 + tx;
    dst[(size_t)n * HH + k] = (_Float16)tile[tx][ty + 8 * p];
  }
}

// Persistent pipelined LSTM: 256 blocks x 512 threads, 1 block/CU (LDS 83KB forces it).
// Blocks 0..127: layer 1 at step t.  Blocks 128..255: layer 2 at step t-1.
// Block owns 8 h-cols (32 feat cols, gate-interleaved nl = 4*m + g).
// Wave w (0..7) owns K slice [256w, 256w+256) of stacked [Wx; Wh]; weights live in
// 64 VGPRs per wave for the WHOLE kernel (no per-step weight traffic, inv-immune).
// Per step: MFMA partials -> LDS reduce -> gate math -> h published via agent-scope
// packed stores (write-through); per-step acquire fence (buffer_inv) on reader side.
__global__ __launch_bounds__(512, 2) void lstm_persist(
    const _Float16* __restrict__ x16, const _Float16* __restrict__ wT,
    const float* __restrict__ bx, const float* __restrict__ bh,
    _Float16* __restrict__ h1buf, _Float16* __restrict__ h2buf,
    float* __restrict__ hmax, unsigned int* __restrict__ bar) {
  __shared__ float part[8][32][72];  // [wave][col][row+pad] = 73,728 B
  __shared__ float red[64][37];      // [row][col+pad]       =  9,472 B  (83,200 total)

  int bid = blockIdx.x;
  int layer = bid >> 7;
  int j = bid & 127;                 // h-cols [8j, 8j+8)
  int tid = threadIdx.x;
  int w = tid >> 6;                  // wave 0..7
  int l = tid & 63;
  int l15 = l & 15, lg = l >> 4;

  // ---- one-time: weight fragments into registers ----
  const _Float16* matp = wT + (size_t)((w < 4 ? 0 : 2) + layer) * G4 * HH;
  int kbase = (w & 3) * 256;
  half8 Breg[16];                    // [kk][c], 64 VGPRs
#pragma unroll
  for (int kk = 0; kk < 8; ++kk) {
#pragma unroll
    for (int c = 0; c < 2; ++c) {
      int nl = 16 * c + l15;                              // block-local col
      int gcol = (nl & 3) * HH + 8 * j + (nl >> 2);       // gate-interleaved
      Breg[kk * 2 + c] = *(const half8*)(matp + (size_t)gcol * HH + kbase + 32 * kk + 8 * lg);
    }
  }

  // ---- per-thread epilogue state (threads 0..255: (row, 2 h-cols)) ----
  int erow = tid >> 2, m2 = tid & 3;
  int hc0 = 8 * j + 2 * m2;
  float bs[8];
  float c0 = 0.f, c1 = 0.f, hm0 = -2.f, hm1 = -2.f;
  if (tid < 256) {
#pragma unroll
    for (int dm = 0; dm < 2; ++dm)
#pragma unroll
      for (int g = 0; g < 4; ++g)
        bs[4 * dm + g] = bx[layer * G4 + g * HH + hc0 + dm] + bh[layer * G4 + g * HH + hc0 + dm];
  }

#pragma unroll 1
  for (int t = 0; t <= SS; ++t) {
    bool active = (layer == 0) ? (t < SS) : (t >= 1);
    if (active) {
      int tp = (layer == 0) ? t : t - 1;
      const _Float16 *A1, *A2;
      _Float16* hout;
      if (layer == 0) {
        A1 = x16 + (size_t)tp * BB * HH;
        A2 = h1buf + (size_t)((tp + 1) & 1) * BB * HH;
        hout = h1buf + (size_t)(tp & 1) * BB * HH;
      } else {
        A1 = h1buf + (size_t)(tp & 1) * BB * HH;
        A2 = h2buf + (size_t)((tp + 1) & 1) * BB * HH;
        hout = h2buf + (size_t)(tp & 1) * BB * HH;
      }
      const _Float16* Aw = (w < 4) ? A1 : A2;
      const _Float16* ap = Aw + (size_t)l15 * HH + kbase + 8 * lg;

      f32x4 acc[8];
#pragma unroll
      for (int i = 0; i < 8; ++i) acc[i] = (f32x4){0.f, 0.f, 0.f, 0.f};

      half8 a[16];
      // half 0: row-frags 0,1
#pragma unroll
      for (int i = 0; i < 16; ++i) {
        int rf = i >> 3, kk = i & 7;
        a[i] = *(const half8*)(ap + (size_t)(16 * rf) * HH + 32 * kk);
      }
#pragma unroll
      for (int i = 0; i < 16; ++i) {
        int rf = i >> 3, kk = i & 7;
        acc[rf * 2 + 0] = __builtin_amdgcn_mfma_f32_16x16x32_f16(a[i], Breg[kk * 2 + 0], acc[rf * 2 + 0], 0, 0, 0);
        acc[rf * 2 + 1] = __builtin_amdgcn_mfma_f32_16x16x32_f16(a[i], Breg[kk * 2 + 1], acc[rf * 2 + 1], 0, 0, 0);
      }
      // half 1: row-frags 2,3
#pragma unroll
      for (int i = 0; i < 16; ++i) {
        int rf = 2 + (i >> 3), kk = i & 7;
        a[i] = *(const half8*)(ap + (size_t)(16 * rf) * HH + 32 * kk);
      }
#pragma unroll
      for (int i = 0; i < 16; ++i) {
        int rf = 2 + (i >> 3), kk = i & 7;
        acc[rf * 2 + 0] = __builtin_amdgcn_mfma_f32_16x16x32_f16(a[i], Breg[kk * 2 + 0], acc[rf * 2 + 0], 0, 0, 0);
        acc[rf * 2 + 1] = __builtin_amdgcn_mfma_f32_16x16x32_f16(a[i], Breg[kk * 2 + 1], acc[rf * 2 + 1], 0, 0, 0);
      }

      // partial K-sums -> LDS (column-vector frags -> b128 stores)
#pragma unroll
      for (int rf = 0; rf < 4; ++rf)
#pragma unroll
        for (int c = 0; c < 2; ++c)
          *(f32x4*)&part[w][16 * c + l15][16 * rf + 4 * lg] = acc[rf * 2 + c];
      __syncthreads();

      // gather across waves (b128) + transpose into red[row][col]
      {
        int col = tid >> 4, rq = tid & 15;
        f32x4 s = {0.f, 0.f, 0.f, 0.f};
#pragma unroll
        for (int ww = 0; ww < 8; ++ww)
          s += *(const f32x4*)&part[ww][col][4 * rq];
        red[4 * rq + 0][col] = s[0];
        red[4 * rq + 1][col] = s[1];
        red[4 * rq + 2][col] = s[2];
        red[4 * rq + 3][col] = s[3];
      }
      __syncthreads();

      // epilogue: 256 threads, each (row, hc0, hc0+1)
      if (tid < 256) {
        float v[8];
#pragma unroll
        for (int q = 0; q < 8; ++q) v[q] = red[erow][8 * m2 + q] + bs[q];
        float i0 = sigmf(v[0]), f0 = sigmf(v[1]), g0 = tanhfast(v[2]), o0 = sigmf(v[3]);
        float i1 = sigmf(v[4]), f1 = sigmf(v[5]), g1 = tanhfast(v[6]), o1 = sigmf(v[7]);
        c0 = f0 * c0 + i0 * g0;
        c1 = f1 * c1 + i1 * g1;
        float h0 = tanhfast(c0) * o0;
        float h1 = tanhfast(c1) * o1;
        if (layer == 1) { hm0 = fmaxf(hm0, h0); hm1 = fmaxf(hm1, h1); }
        unsigned int pk = ((unsigned int)__builtin_bit_cast(unsigned short, (_Float16)h1) << 16) |
                          (unsigned int)__builtin_bit_cast(unsigned short, (_Float16)h0);
        // agent-scope write-through: lands at device coherence point, no wbl2 needed
        __hip_atomic_store((unsigned int*)hout + ((erow * HH + hc0) >> 1), pk,
                           __ATOMIC_RELAXED, __HIP_MEMORY_SCOPE_AGENT);
      }
    }

    // ---- grid barrier (two-level, monotonic counters) ----
    __syncthreads();  // drains each wave's vmcnt: all h-stores at coherence point
    if (tid == 0) {
      unsigned int* gcnt = bar + (bid & 7) * 64;
      unsigned int prev = __hip_atomic_fetch_add(gcnt, 1u, __ATOMIC_RELAXED, __HIP_MEMORY_SCOPE_AGENT);
      if (prev == 32u * (unsigned)(t + 1) - 1u)
        __hip_atomic_fetch_add(bar + 512, 1u, __ATOMIC_RELAXED, __HIP_MEMORY_SCOPE_AGENT);
      while (__hip_atomic_load(bar + 512, __ATOMIC_RELAXED, __HIP_MEMORY_SCOPE_AGENT) <
             8u * (unsigned)(t + 1))
        __builtin_amdgcn_s_sleep(2);
      __builtin_amdgcn_fence(__ATOMIC_ACQUIRE, "agent");  // inv L1 + XCD L2: see fresh h
    }
    __syncthreads();
  }

  if (layer == 1 && tid < 256) {
    hmax[erow * HH + hc0]     = hm0;
    hmax[erow * HH + hc0 + 1] = hm1;
  }
}

__global__ __launch_bounds__(320) void classify_kernel(const float* __restrict__ hmax,
                                                       const float* __restrict__ Wp,
                                                       const float* __restrict__ bp,
                                                       float* __restrict__ out) {
  int tid = threadIdx.x;  // 320 = 64*5
  int b = tid / 5, jj = tid % 5;
  float s = bp[jj];
  const float* hp = hmax + (size_t)b * HH;
  for (int h = 0; h < HH; ++h) s = fmaf(hp[h], Wp[h * 5 + jj], s);
  out[tid] = s;
}

extern "C" void kernel_launch(void* const* d_in, const int* in_sizes, int n_in,
                              void* d_out, int out_size, void* d_ws, size_t ws_size,
                              hipStream_t stream) {
  const float* inputs = (const float*)d_in[0];
  const float* Wx = (const float*)d_in[1];
  const float* bx = (const float*)d_in[2];
  const float* Wh = (const float*)d_in[3];
  const float* bh = (const float*)d_in[4];
  const float* Wp = (const float*)d_in[5];
  const float* bp = (const float*)d_in[6];
  float* out = (float*)d_out;

  char* ws = (char*)d_ws;
  _Float16* x16   = (_Float16*)(ws + 0);           // 67,108,864
  _Float16* wT    = (_Float16*)(ws + 67108864);    // 33,554,432
  _Float16* h1buf = (_Float16*)(ws + 100663296);   // 2*64*1024*2 = 262,144
  _Float16* h2buf = (_Float16*)(ws + 100925440);   // 262,144
  float*    hmax  = (float*)(ws + 101187584);      // 262,144
  unsigned int* bar = (unsigned int*)(ws + 101449728);  // 4,096

  hipMemsetAsync(h1buf, 0, 262144, stream);
  hipMemsetAsync(h2buf, 0, 262144, stream);
  hipMemsetAsync(bar, 0, 4096, stream);

  convert_x_kernel<<<32768, 256, 0, stream>>>(inputs, x16);
  convert_w_kernel<<<16384, 256, 0, stream>>>(Wx, Wh, wT);
  lstm_persist<<<256, 512, 0, stream>>>(x16, wT, bx, bh, h1buf, h2buf, hmax, bar);
  classify_kernel<<<1, 320, 0, stream>>>(hmax, Wp, bp, out);
}

// Round 3
// 5195.407 us; speedup vs baseline: 3.8628x; 1.2282x over previous
//
#include <hip/hip_runtime.h>
#include <hip/hip_bf16.h>

typedef _Float16 half8 __attribute__((ext_vector_type(8)));
typedef _Float16 half4v __attribute__((ext_vector_type(4)));
typedef float f32x4 __attribute__((ext_vector_type(4)));

#define BB 64
#define SS 512
#define HH 1024
#define G4 4096
#define NSTEP 514   // layer1: t in [0,512); layer2 (skew 2): t in [2,514)

// bar word indices: arrive[g]=32*g, global=256, go[g]=288+32*g
#define BAR_GLB 256
#define BAR_GO  288

__device__ __forceinline__ float sigmf(float x) { return 1.0f / (1.0f + __expf(-x)); }
__device__ __forceinline__ float tanhfast(float x) { return 2.0f / (1.0f + __expf(-2.0f * x)) - 1.0f; }

// inputs[b][s][h] (f32) -> x16[s][b][h] (fp16), time-major
__global__ __launch_bounds__(256) void convert_x_kernel(const float* __restrict__ in,
                                                        _Float16* __restrict__ x16) {
  size_t idx = (size_t)blockIdx.x * 256 + threadIdx.x;  // 8,388,608 float4s
  int h4 = (int)(idx & 255);
  int s  = (int)((idx >> 8) & 511);
  int b  = (int)(idx >> 17);
  const float4* src = (const float4*)in;
  float4 v = src[((size_t)b * SS + s) * 256 + h4];
  half4v hv = { (_Float16)v.x, (_Float16)v.y, (_Float16)v.z, (_Float16)v.w };
  *(half4v*)(x16 + ((size_t)s * BB + b) * HH + (size_t)h4 * 4) = hv;
}

// W[l][k][n] (f32) -> wT[m][n][k] (fp16); m: 0=Wx l0, 1=Wx l1, 2=Wh l0, 3=Wh l1
__global__ __launch_bounds__(256) void convert_w_kernel(const float* __restrict__ Wx,
                                                        const float* __restrict__ Wh,
                                                        _Float16* __restrict__ wT) {
  __shared__ float tile[32][33];
  int m = blockIdx.x >> 12;        // 4096 tiles per matrix
  int t = blockIdx.x & 4095;
  int tn = t & 127, tk = t >> 7;   // 128 n-tiles, 32 k-tiles
  int l = m & 1, which = m >> 1;
  const float* src = (which ? Wh : Wx) + (size_t)l * HH * G4;
  int tx = threadIdx.x & 31, ty = threadIdx.x >> 5;  // ty 0..7
#pragma unroll
  for (int p = 0; p < 4; ++p) {
    int k = tk * 32 + ty + 8 * p, n = tn * 32 + tx;
    tile[ty + 8 * p][tx] = src[(size_t)k * G4 + n];
  }
  __syncthreads();
  _Float16* dst = wT + (size_t)m * G4 * HH;
#pragma unroll
  for (int p = 0; p < 4; ++p) {
    int n = tn * 32 + ty + 8 * p, k = tk * 32 + tx;
    dst[(size_t)n * HH + k] = (_Float16)tile[tx][ty + 8 * p];
  }
}

// Persistent pipelined LSTM, 256 blocks x 512 threads, 1 block/CU (83KB LDS).
// Blocks 0..127: layer1 timestep t.  Blocks 128..255: layer2 timestep t-2 (2-skew).
// Per block: 8 h-cols (32 gate-interleaved feat cols), all 64 rows.
// Wave w owns K-slice [128w,128w+128) of BOTH the input-half (Wx) and the
// recurrent-half (Wh); weights live in 64 VGPRs for the whole kernel.
// Per iteration: input-half MFMAs run BEFORE the barrier poll (inputs are one
// barrier old); only the recurrent half + reduce + epilogue are post-detect.
// Release is a fan-out tree: group arrive lines -> global line -> 8 go words.
__global__ __launch_bounds__(512, 2) void lstm_persist(
    const _Float16* __restrict__ x16, const _Float16* __restrict__ wT,
    const float* __restrict__ bx, const float* __restrict__ bh,
    _Float16* __restrict__ h1buf, _Float16* __restrict__ h2buf,
    float* __restrict__ hmax, unsigned int* __restrict__ bar) {
  __shared__ float part[8][32][72];  // [wave][col][row+pad] = 73,728 B
  __shared__ float red[64][37];      // [row][col+pad]       =  9,472 B

  const int bid = blockIdx.x;
  const int layer = bid >> 7;
  const int j = bid & 127;           // h-cols [8j, 8j+8)
  const int tid = threadIdx.x;
  const int w = tid >> 6, l = tid & 63;
  const int l15 = l & 15, lg = l >> 4;
  const int grp = bid & 7;

  // ---- one-time: weight fragments into registers ----
  const _Float16* wTe = wT + (size_t)layer * G4 * HH;        // input-half: Wx of this layer
  const _Float16* wTr = wT + (size_t)(2 + layer) * G4 * HH;  // recurrent-half: Wh
  const int kbase = w * 128;
  half8 Be[8], Br[8];                // [kk][c]: 4 k-steps x 2 col-frags each
#pragma unroll
  for (int kk = 0; kk < 4; ++kk)
#pragma unroll
    for (int c = 0; c < 2; ++c) {
      int nl = 16 * c + l15;
      size_t gcol = (size_t)((nl & 3) * HH + 8 * j + (nl >> 2));
      Be[kk * 2 + c] = *(const half8*)(wTe + gcol * HH + kbase + 32 * kk + 8 * lg);
      Br[kk * 2 + c] = *(const half8*)(wTr + gcol * HH + kbase + 32 * kk + 8 * lg);
    }

  // ---- per-thread epilogue state (threads 0..255: (row, 2 h-cols)) ----
  const int erow = tid >> 2, m2 = tid & 3;
  const int hc0 = 8 * j + 2 * m2;
  float bs[8];
  float c0 = 0.f, c1 = 0.f, hm0 = -2.f, hm1 = -2.f;
  if (tid < 256) {
#pragma unroll
    for (int dm = 0; dm < 2; ++dm)
#pragma unroll
      for (int g = 0; g < 4; ++g)
        bs[4 * dm + g] = bx[layer * G4 + g * HH + hc0 + dm] + bh[layer * G4 + g * HH + hc0 + dm];
  }

#pragma unroll 1
  for (int t = 0; t < NSTEP; ++t) {
    const bool act = (layer == 0) ? (t < SS) : (t >= 2);
    f32x4 acc[8];
#pragma unroll
    for (int i = 0; i < 8; ++i) acc[i] = (f32x4){0.f, 0.f, 0.f, 0.f};

    // ---- Phase A (pre-detect): input-half. L1: x_t @ Wx1. L2: h1_{t-2} @ Wx2.
    // Inputs were released >=1 barrier ago; last iteration's acquire fence makes
    // cached copies fresh. Concurrent writers target slot t&3 != (t-2)&3.
    if (act) {
      const _Float16* Ae = (layer == 0) ? x16 + (size_t)t * BB * HH
                                        : h1buf + (size_t)((t - 2) & 3) * BB * HH;
      const _Float16* aep = Ae + (size_t)l15 * HH + kbase + 8 * lg;
      half8 a[16];
#pragma unroll
      for (int rf = 0; rf < 4; ++rf)
#pragma unroll
        for (int kk = 0; kk < 4; ++kk)
          a[rf * 4 + kk] = *(const half8*)(aep + (size_t)(16 * rf) * HH + 32 * kk);
#pragma unroll
      for (int rf = 0; rf < 4; ++rf)
#pragma unroll
        for (int kk = 0; kk < 4; ++kk) {
          acc[rf * 2 + 0] = __builtin_amdgcn_mfma_f32_16x16x32_f16(a[rf * 4 + kk], Be[kk * 2 + 0], acc[rf * 2 + 0], 0, 0, 0);
          acc[rf * 2 + 1] = __builtin_amdgcn_mfma_f32_16x16x32_f16(a[rf * 4 + kk], Be[kk * 2 + 1], acc[rf * 2 + 1], 0, 0, 0);
        }
    }

    // ---- Phase B: wait for barrier t-1 (go[grp] >= t), then acquire.
    if (tid == 0) {
      while (__hip_atomic_load(bar + BAR_GO + 32 * grp, __ATOMIC_RELAXED,
                               __HIP_MEMORY_SCOPE_AGENT) < (unsigned)t)
        __builtin_amdgcn_s_sleep(1);
      __builtin_amdgcn_fence(__ATOMIC_ACQUIRE, "agent");  // inv L1+L2: fresh h below
    }
    __syncthreads();

    // ---- Phase C (post-detect): recurrent half + reduce + epilogue + publish.
    if (act) {
      const _Float16* Ah = (layer == 0) ? h1buf + (size_t)((t - 1) & 3) * BB * HH   // h1_{t-1}
                                        : h2buf + (size_t)((t - 1) & 1) * BB * HH;  // h2_{t-3}
      const _Float16* ahp = Ah + (size_t)l15 * HH + kbase + 8 * lg;
      half8 a[16];
#pragma unroll
      for (int rf = 0; rf < 4; ++rf)
#pragma unroll
        for (int kk = 0; kk < 4; ++kk)
          a[rf * 4 + kk] = *(const half8*)(ahp + (size_t)(16 * rf) * HH + 32 * kk);
#pragma unroll
      for (int rf = 0; rf < 4; ++rf)
#pragma unroll
        for (int kk = 0; kk < 4; ++kk) {
          acc[rf * 2 + 0] = __builtin_amdgcn_mfma_f32_16x16x32_f16(a[rf * 4 + kk], Br[kk * 2 + 0], acc[rf * 2 + 0], 0, 0, 0);
          acc[rf * 2 + 1] = __builtin_amdgcn_mfma_f32_16x16x32_f16(a[rf * 4 + kk], Br[kk * 2 + 1], acc[rf * 2 + 1], 0, 0, 0);
        }

      // partial K-sums -> LDS
#pragma unroll
      for (int rf = 0; rf < 4; ++rf)
#pragma unroll
        for (int c = 0; c < 2; ++c)
          *(f32x4*)&part[w][16 * c + l15][16 * rf + 4 * lg] = acc[rf * 2 + c];
      __syncthreads();

      {  // gather across waves + transpose into red[row][col]
        int col = tid >> 4, rq = tid & 15;
        f32x4 s = {0.f, 0.f, 0.f, 0.f};
#pragma unroll
        for (int ww = 0; ww < 8; ++ww)
          s += *(const f32x4*)&part[ww][col][4 * rq];
        red[4 * rq + 0][col] = s[0];
        red[4 * rq + 1][col] = s[1];
        red[4 * rq + 2][col] = s[2];
        red[4 * rq + 3][col] = s[3];
      }
      __syncthreads();

      if (tid < 256) {
        float v[8];
#pragma unroll
        for (int q = 0; q < 8; ++q) v[q] = red[erow][8 * m2 + q] + bs[q];
        float i0 = sigmf(v[0]), f0 = sigmf(v[1]), g0 = tanhfast(v[2]), o0 = sigmf(v[3]);
        float i1 = sigmf(v[4]), f1 = sigmf(v[5]), g1 = tanhfast(v[6]), o1 = sigmf(v[7]);
        c0 = f0 * c0 + i0 * g0;
        c1 = f1 * c1 + i1 * g1;
        float h0 = tanhfast(c0) * o0;
        float h1 = tanhfast(c1) * o1;
        if (layer == 1) { hm0 = fmaxf(hm0, h0); hm1 = fmaxf(hm1, h1); }
        _Float16* hout = (layer == 0) ? h1buf + (size_t)(t & 3) * BB * HH
                                      : h2buf + (size_t)(t & 1) * BB * HH;
        unsigned int pk = ((unsigned int)__builtin_bit_cast(unsigned short, (_Float16)h1) << 16) |
                          (unsigned int)__builtin_bit_cast(unsigned short, (_Float16)h0);
        __hip_atomic_store((unsigned int*)hout + ((erow * HH + hc0) >> 1), pk,
                           __ATOMIC_RELAXED, __HIP_MEMORY_SCOPE_AGENT);
      }
    }

    // ---- arrive at barrier t (syncthreads drains the h publishes first) ----
    __syncthreads();
    if (tid == 0) {
      unsigned prev = __hip_atomic_fetch_add(bar + 32 * grp, 1u, __ATOMIC_RELAXED,
                                             __HIP_MEMORY_SCOPE_AGENT);
      if (prev == 32u * (unsigned)(t + 1) - 1u) {
        unsigned p2 = __hip_atomic_fetch_add(bar + BAR_GLB, 1u, __ATOMIC_RELAXED,
                                             __HIP_MEMORY_SCOPE_AGENT);
        if (p2 == 8u * (unsigned)(t + 1) - 1u) {
#pragma unroll
          for (int gg = 0; gg < 8; ++gg)
            __hip_atomic_store(bar + BAR_GO + 32 * gg, (unsigned)(t + 1),
                               __ATOMIC_RELAXED, __HIP_MEMORY_SCOPE_AGENT);
        }
      }
    }
  }

  if (layer == 1 && tid < 256) {
    hmax[erow * HH + hc0]     = hm0;
    hmax[erow * HH + hc0 + 1] = hm1;
  }
}

__global__ __launch_bounds__(320) void classify_kernel(const float* __restrict__ hmax,
                                                       const float* __restrict__ Wp,
                                                       const float* __restrict__ bp,
                                                       float* __restrict__ out) {
  int tid = threadIdx.x;  // 320 = 64*5
  int b = tid / 5, jj = tid % 5;
  float s = bp[jj];
  const float* hp = hmax + (size_t)b * HH;
  for (int h = 0; h < HH; ++h) s = fmaf(hp[h], Wp[h * 5 + jj], s);
  out[tid] = s;
}

extern "C" void kernel_launch(void* const* d_in, const int* in_sizes, int n_in,
                              void* d_out, int out_size, void* d_ws, size_t ws_size,
                              hipStream_t stream) {
  const float* inputs = (const float*)d_in[0];
  const float* Wx = (const float*)d_in[1];
  const float* bx = (const float*)d_in[2];
  const float* Wh = (const float*)d_in[3];
  const float* bh = (const float*)d_in[4];
  const float* Wp = (const float*)d_in[5];
  const float* bp = (const float*)d_in[6];
  float* out = (float*)d_out;

  char* ws = (char*)d_ws;
  _Float16* x16   = (_Float16*)(ws + 0);           // 67,108,864
  _Float16* wT    = (_Float16*)(ws + 67108864);    // 33,554,432
  _Float16* h1buf = (_Float16*)(ws + 100663296);   // 4 slots * 131072 = 524,288
  _Float16* h2buf = (_Float16*)(ws + 101187584);   // 2 slots * 131072 = 262,144
  float*    hmax  = (float*)(ws + 101449728);      // 262,144
  unsigned int* bar = (unsigned int*)(ws + 101711872);  // 4,096

  hipMemsetAsync(h1buf, 0, 524288, stream);
  hipMemsetAsync(h2buf, 0, 262144, stream);
  hipMemsetAsync(bar, 0, 4096, stream);

  convert_x_kernel<<<32768, 256, 0, stream>>>(inputs, x16);
  convert_w_kernel<<<16384, 256, 0, stream>>>(Wx, Wh, wT);
  lstm_persist<<<256, 512, 0, stream>>>(x16, wT, bx, bh, h1buf, h2buf, hmax, bar);
  classify_kernel<<<1, 320, 0, stream>>>(hmax, Wp, bp, out);
}

// Round 5
// 4822.005 us; speedup vs baseline: 4.1620x; 1.0774x over previous
//
#include <hip/hip_runtime.h>
#include <hip/hip_bf16.h>

typedef _Float16 half8 __attribute__((ext_vector_type(8)));
typedef _Float16 half4v __attribute__((ext_vector_type(4)));
typedef float f32x4 __attribute__((ext_vector_type(4)));

#define BB 64
#define SS 512
#define HH 1024
#define G4 4096
#define NSTEP 514
#define SLOT 65536  // elements per h matrix (64*1024 fp16 = 131072 B)

// SAFE-mode barrier words (identical to round-3 layout)
#define SB_ARR(g) ((g) * 32)
#define SB_GLB 256
#define SB_GO(g) (288 + (g) * 32)
// FAST-mode (trajectory) barrier words: per-layer arrive/global/go
#define FB_ARR(L, g) ((L) * 256 + (g) * 32)
#define FB_GLB(L) (512 + (L) * 32)
#define FB_GO(L, g) (576 + (L) * 256 + (g) * 32)

__device__ __forceinline__ float sigmf(float x) { return 1.0f / (1.0f + __expf(-x)); }
__device__ __forceinline__ float tanhfast(float x) { return 2.0f / (1.0f + __expf(-2.0f * x)) - 1.0f; }

__device__ __forceinline__ unsigned aload(const unsigned* p) {
  return __hip_atomic_load(p, __ATOMIC_RELAXED, __HIP_MEMORY_SCOPE_AGENT);
}
__device__ __forceinline__ void wait_ge(const unsigned* p, unsigned tgt) {
  while (aload(p) < tgt) __builtin_amdgcn_s_sleep(1);
}
__device__ __forceinline__ unsigned aadd(unsigned* p) {
  return __hip_atomic_fetch_add(p, 1u, __ATOMIC_RELAXED, __HIP_MEMORY_SCOPE_AGENT);
}
__device__ __forceinline__ void astore(unsigned* p, unsigned v) {
  __hip_atomic_store(p, v, __ATOMIC_RELAXED, __HIP_MEMORY_SCOPE_AGENT);
}

// inputs[b][s][h] (f32) -> x16[s][b][h] (fp16), time-major
__global__ __launch_bounds__(256) void convert_x_kernel(const float* __restrict__ in,
                                                        _Float16* __restrict__ x16) {
  size_t idx = (size_t)blockIdx.x * 256 + threadIdx.x;
  int h4 = (int)(idx & 255);
  int s  = (int)((idx >> 8) & 511);
  int b  = (int)(idx >> 17);
  const float4* src = (const float4*)in;
  float4 v = src[((size_t)b * SS + s) * 256 + h4];
  half4v hv = { (_Float16)v.x, (_Float16)v.y, (_Float16)v.z, (_Float16)v.w };
  *(half4v*)(x16 + ((size_t)s * BB + b) * HH + (size_t)h4 * 4) = hv;
}

// W[l][k][n] (f32) -> wT[m][n][k] (fp16); m: 0=Wx l0, 1=Wx l1, 2=Wh l0, 3=Wh l1
__global__ __launch_bounds__(256) void convert_w_kernel(const float* __restrict__ Wx,
                                                        const float* __restrict__ Wh,
                                                        _Float16* __restrict__ wT) {
  __shared__ float tile[32][33];
  int m = blockIdx.x >> 12;
  int t = blockIdx.x & 4095;
  int tn = t & 127, tk = t >> 7;
  int l = m & 1, which = m >> 1;
  const float* src = (which ? Wh : Wx) + (size_t)l * HH * G4;
  int tx = threadIdx.x & 31, ty = threadIdx.x >> 5;
#pragma unroll
  for (int p = 0; p < 4; ++p) {
    int k = tk * 32 + ty + 8 * p, n = tn * 32 + tx;
    tile[ty + 8 * p][tx] = src[(size_t)k * G4 + n];
  }
  __syncthreads();
  _Float16* dst = wT + (size_t)m * G4 * HH;
#pragma unroll
  for (int p = 0; p < 4; ++p) {
    int n = tn * 32 + ty + 8 * p, k = tk * 32 + tx;
    dst[(size_t)n * HH + k] = (_Float16)tile[tx][ty + 8 * p];
  }
}

// Persistent pipelined LSTM, 256 blocks x 512 threads, 1 block/CU (83KB LDS).
// Blocks 0..127: layer1 step t.  Blocks 128..255: layer2 step t-2 (2-skew).
// TRAJ=true  : fresh h slot per timestep (513-slot trajectories) -> consumer L2
//              misses are compulsory -> NO acquire fence ever; weights/x16 stay
//              L2-warm. Split per-layer barriers; L1 free-runs ahead of L2.
//              DEADLOCK FIX vs R4: Phase-B wait is UNCONDITIONAL (even when
//              act==false) so arrivals stay iteration-ordered -- the
//              prev==N*(t+1)-1 release triggers require ordered arrivals.
// TRAJ=false : round-3 proven behavior (rings + per-step acquire fence).
template <bool TRAJ>
__global__ __launch_bounds__(512, 2) void lstm_persist(
    const _Float16* __restrict__ x16, const _Float16* __restrict__ wT,
    const float* __restrict__ bx, const float* __restrict__ bh,
    _Float16* __restrict__ h1buf, _Float16* __restrict__ h2buf,
    float* __restrict__ hmax, unsigned* __restrict__ bar) {
  __shared__ float part[8][32][72];  // [wave][col][row+pad] = 73,728 B
  __shared__ float red[64][37];      // [row][col+pad]       =  9,472 B

  const int bid = blockIdx.x;
  const int layer = bid >> 7;
  const int j = bid & 127;           // h-cols [8j, 8j+8)
  const int tid = threadIdx.x;
  const int w = tid >> 6, l = tid & 63;
  const int l15 = l & 15, lg = l >> 4;
  const int grp = bid & 7;

  // ---- one-time: weight fragments into registers ----
  const _Float16* wTe = wT + (size_t)layer * G4 * HH;        // Wx of this layer
  const _Float16* wTr = wT + (size_t)(2 + layer) * G4 * HH;  // Wh of this layer
  const int kbase = w * 128;
  half8 Be[8], Br[8];
#pragma unroll
  for (int kk = 0; kk < 4; ++kk)
#pragma unroll
    for (int c = 0; c < 2; ++c) {
      int nl = 16 * c + l15;
      size_t gcol = (size_t)((nl & 3) * HH + 8 * j + (nl >> 2));
      Be[kk * 2 + c] = *(const half8*)(wTe + gcol * HH + kbase + 32 * kk + 8 * lg);
      Br[kk * 2 + c] = *(const half8*)(wTr + gcol * HH + kbase + 32 * kk + 8 * lg);
    }

  // ---- per-thread epilogue state (threads 0..255: (row, 2 h-cols)) ----
  const int erow = tid >> 2, m2 = tid & 3;
  const int hc0 = 8 * j + 2 * m2;
  float bs[8];
  float c0 = 0.f, c1 = 0.f, hm0 = -2.f, hm1 = -2.f;
  if (tid < 256) {
#pragma unroll
    for (int dm = 0; dm < 2; ++dm)
#pragma unroll
      for (int g = 0; g < 4; ++g)
        bs[4 * dm + g] = bx[layer * G4 + g * HH + hc0 + dm] + bh[layer * G4 + g * HH + hc0 + dm];
  }

  const int tmax = TRAJ ? (layer ? NSTEP : SS) : NSTEP;

#pragma unroll 1
  for (int t = 0; t < tmax; ++t) {
    const bool act = (layer == 0) ? (t < SS) : (t >= 2);
    f32x4 acc[8];
#pragma unroll
    for (int i = 0; i < 8; ++i) acc[i] = (f32x4){0.f, 0.f, 0.f, 0.f};

    // ---- Phase A: input-half. L1: x_t @ Wx1. L2: h1_{t-2} @ Wx2.
    if (act) {
      const _Float16* Ae;
      if (layer == 0) {
        Ae = x16 + (size_t)t * SLOT;
      } else if (TRAJ) {
        // gate BEFORE touching the trajectory slot: an early read would cache
        // an unwritten line and break freshness-by-construction.
        if (tid == 0) wait_ge(bar + FB_GO(0, grp), (unsigned)(t - 1));
        __syncthreads();
        Ae = h1buf + (size_t)(t - 1) * SLOT;  // h1[t-2] -> slot t-1
      } else {
        Ae = h1buf + (size_t)((t - 2) & 3) * SLOT;
      }
      const _Float16* aep = Ae + (size_t)l15 * HH + kbase + 8 * lg;
      half8 a[16];
#pragma unroll
      for (int rf = 0; rf < 4; ++rf)
#pragma unroll
        for (int kk = 0; kk < 4; ++kk)
          a[rf * 4 + kk] = *(const half8*)(aep + (size_t)(16 * rf) * HH + 32 * kk);
#pragma unroll
      for (int rf = 0; rf < 4; ++rf)
#pragma unroll
        for (int kk = 0; kk < 4; ++kk) {
          acc[rf * 2 + 0] = __builtin_amdgcn_mfma_f32_16x16x32_f16(a[rf * 4 + kk], Be[kk * 2 + 0], acc[rf * 2 + 0], 0, 0, 0);
          acc[rf * 2 + 1] = __builtin_amdgcn_mfma_f32_16x16x32_f16(a[rf * 4 + kk], Be[kk * 2 + 1], acc[rf * 2 + 1], 0, 0, 0);
        }
    }

    // ---- Phase B: wait for own-layer barrier t-1. UNCONDITIONAL (deadlock fix).
    if (tid == 0) {
      if (TRAJ) {
        wait_ge(bar + FB_GO(layer, grp), (unsigned)t);
      } else {
        wait_ge(bar + SB_GO(grp), (unsigned)t);
        __builtin_amdgcn_fence(__ATOMIC_ACQUIRE, "agent");  // SAFE mode only
      }
    }
    __syncthreads();

    // ---- Phase C: recurrent half + reduce + epilogue + publish.
    if (act) {
      const _Float16* Ah;
      if (layer == 0)
        Ah = TRAJ ? h1buf + (size_t)t * SLOT           // h1[t-1] -> slot t
                  : h1buf + (size_t)((t - 1) & 3) * SLOT;
      else
        Ah = TRAJ ? h2buf + (size_t)(t - 2) * SLOT     // h2[t-3] -> slot t-2
                  : h2buf + (size_t)((t - 1) & 1) * SLOT;
      const _Float16* ahp = Ah + (size_t)l15 * HH + kbase + 8 * lg;
      half8 a[16];
#pragma unroll
      for (int rf = 0; rf < 4; ++rf)
#pragma unroll
        for (int kk = 0; kk < 4; ++kk)
          a[rf * 4 + kk] = *(const half8*)(ahp + (size_t)(16 * rf) * HH + 32 * kk);
#pragma unroll
      for (int rf = 0; rf < 4; ++rf)
#pragma unroll
        for (int kk = 0; kk < 4; ++kk) {
          acc[rf * 2 + 0] = __builtin_amdgcn_mfma_f32_16x16x32_f16(a[rf * 4 + kk], Br[kk * 2 + 0], acc[rf * 2 + 0], 0, 0, 0);
          acc[rf * 2 + 1] = __builtin_amdgcn_mfma_f32_16x16x32_f16(a[rf * 4 + kk], Br[kk * 2 + 1], acc[rf * 2 + 1], 0, 0, 0);
        }

#pragma unroll
      for (int rf = 0; rf < 4; ++rf)
#pragma unroll
        for (int c = 0; c < 2; ++c)
          *(f32x4*)&part[w][16 * c + l15][16 * rf + 4 * lg] = acc[rf * 2 + c];
      __syncthreads();

      {  // gather across waves + transpose into red[row][col]
        int col = tid >> 4, rq = tid & 15;
        f32x4 s = {0.f, 0.f, 0.f, 0.f};
#pragma unroll
        for (int ww = 0; ww < 8; ++ww)
          s += *(const f32x4*)&part[ww][col][4 * rq];
        red[4 * rq + 0][col] = s[0];
        red[4 * rq + 1][col] = s[1];
        red[4 * rq + 2][col] = s[2];
        red[4 * rq + 3][col] = s[3];
      }
      __syncthreads();

      if (tid < 256) {
        float v[8];
#pragma unroll
        for (int q = 0; q < 8; ++q) v[q] = red[erow][8 * m2 + q] + bs[q];
        float i0 = sigmf(v[0]), f0 = sigmf(v[1]), g0 = tanhfast(v[2]), o0 = sigmf(v[3]);
        float i1 = sigmf(v[4]), f1 = sigmf(v[5]), g1 = tanhfast(v[6]), o1 = sigmf(v[7]);
        c0 = f0 * c0 + i0 * g0;
        c1 = f1 * c1 + i1 * g1;
        float h0 = tanhfast(c0) * o0;
        float h1 = tanhfast(c1) * o1;
        if (layer == 1) { hm0 = fmaxf(hm0, h0); hm1 = fmaxf(hm1, h1); }
        _Float16* hout;
        if (layer == 0)
          hout = TRAJ ? h1buf + (size_t)(t + 1) * SLOT : h1buf + (size_t)(t & 3) * SLOT;
        else
          hout = TRAJ ? h2buf + (size_t)(t - 1) * SLOT : h2buf + (size_t)(t & 1) * SLOT;
        unsigned pk = ((unsigned)__builtin_bit_cast(unsigned short, (_Float16)h1) << 16) |
                      (unsigned)__builtin_bit_cast(unsigned short, (_Float16)h0);
        astore((unsigned*)hout + ((erow * HH + hc0) >> 1), pk);  // sc1 write-through
      }
    }

    // ---- arrive (syncthreads drains all waves' publishes first) ----
    __syncthreads();
    if (tid == 0) {
      if (TRAJ) {
        unsigned prev = aadd(bar + FB_ARR(layer, grp));
        if (prev == 16u * (unsigned)(t + 1) - 1u) {
          unsigned p2 = aadd(bar + FB_GLB(layer));
          if (p2 == 8u * (unsigned)(t + 1) - 1u) {
#pragma unroll
            for (int gg = 0; gg < 8; ++gg)
              astore(bar + FB_GO(layer, gg), (unsigned)(t + 1));
          }
        }
      } else {
        unsigned prev = aadd(bar + SB_ARR(grp));
        if (prev == 32u * (unsigned)(t + 1) - 1u) {
          unsigned p2 = aadd(bar + SB_GLB);
          if (p2 == 8u * (unsigned)(t + 1) - 1u) {
#pragma unroll
            for (int gg = 0; gg < 8; ++gg)
              astore(bar + SB_GO(gg), (unsigned)(t + 1));
          }
        }
      }
    }
  }

  if (layer == 1 && tid < 256) {
    hmax[erow * HH + hc0]     = hm0;
    hmax[erow * HH + hc0 + 1] = hm1;
  }
}

__global__ __launch_bounds__(320) void classify_kernel(const float* __restrict__ hmax,
                                                       const float* __restrict__ Wp,
                                                       const float* __restrict__ bp,
                                                       float* __restrict__ out) {
  int tid = threadIdx.x;  // 320 = 64*5
  int b = tid / 5, jj = tid % 5;
  float s = bp[jj];
  const float* hp = hmax + (size_t)b * HH;
  for (int h = 0; h < HH; ++h) s = fmaf(hp[h], Wp[h * 5 + jj], s);
  out[tid] = s;
}

extern "C" void kernel_launch(void* const* d_in, const int* in_sizes, int n_in,
                              void* d_out, int out_size, void* d_ws, size_t ws_size,
                              hipStream_t stream) {
  const float* inputs = (const float*)d_in[0];
  const float* Wx = (const float*)d_in[1];
  const float* bx = (const float*)d_in[2];
  const float* Wh = (const float*)d_in[3];
  const float* bh = (const float*)d_in[4];
  const float* Wp = (const float*)d_in[5];
  const float* bp = (const float*)d_in[6];
  float* out = (float*)d_out;

  char* ws = (char*)d_ws;
  _Float16* x16 = (_Float16*)(ws + 0);          // 67,108,864
  _Float16* wT  = (_Float16*)(ws + 67108864);   // 33,554,432 -> 100,663,296

  // FAST (trajectory) layout: h1 traj 513 slots, h2 traj 513 slots
  const size_t TRAJ_BYTES = (size_t)513 * 131072;           // 67,239,936
  const size_t NEED_FAST = 100663296ull + 2 * TRAJ_BYTES + 262144 + 8192;  // 235,413,504
  bool fast = ws_size >= NEED_FAST;

  convert_x_kernel<<<32768, 256, 0, stream>>>(inputs, x16);
  convert_w_kernel<<<16384, 256, 0, stream>>>(Wx, Wh, wT);

  if (fast) {
    _Float16* h1traj = (_Float16*)(ws + 100663296);
    _Float16* h2traj = (_Float16*)(ws + 100663296 + TRAJ_BYTES);
    float* hmax = (float*)(ws + 100663296 + 2 * TRAJ_BYTES);
    unsigned* bar = (unsigned*)(ws + 100663296 + 2 * TRAJ_BYTES + 262144);
    hipMemsetAsync(h1traj, 0, 131072, stream);  // zero slot (t = -1)
    hipMemsetAsync(h2traj, 0, 131072, stream);
    hipMemsetAsync(bar, 0, 8192, stream);
    lstm_persist<true><<<256, 512, 0, stream>>>(x16, wT, bx, bh, h1traj, h2traj, hmax, bar);
    classify_kernel<<<1, 320, 0, stream>>>(hmax, Wp, bp, out);
  } else {
    _Float16* h1buf = (_Float16*)(ws + 100663296);          // 4 slots
    _Float16* h2buf = (_Float16*)(ws + 101187584);          // 2 slots
    float* hmax = (float*)(ws + 101449728);
    unsigned* bar = (unsigned*)(ws + 101711872);
    hipMemsetAsync(h1buf, 0, 524288, stream);
    hipMemsetAsync(h2buf, 0, 262144, stream);
    hipMemsetAsync(bar, 0, 8192, stream);
    lstm_persist<false><<<256, 512, 0, stream>>>(x16, wT, bx, bh, h1buf, h2buf, hmax, bar);
    classify_kernel<<<1, 320, 0, stream>>>(hmax, Wp, bp, out);
  }
}